// Round 1
// baseline (233.311 us; speedup 1.0000x reference)
//
#include <hip/hip_runtime.h>

#define MROWS 16384
#define KD 2048
#define NQ 256
#define NE 64
#define INV_SQRT_DQ 0.0625f
#define NOISE_STD_C 0.1f

typedef _Float16 f16x8 __attribute__((ext_vector_type(8)));
typedef float f32x4 __attribute__((ext_vector_type(4)));

__device__ inline void split8v(f32x4 a, f32x4 b, f16x8* h, f16x8* l) {
    f16x8 hh, ll;
#pragma unroll
    for (int i = 0; i < 4; ++i) {
        _Float16 s = (_Float16)a[i];
        hh[i] = s; ll[i] = (_Float16)(a[i] - (float)s);
    }
#pragma unroll
    for (int i = 0; i < 4; ++i) {
        _Float16 s = (_Float16)b[i];
        hh[4 + i] = s; ll[4 + i] = (_Float16)(b[i] - (float)s);
    }
    *h = hh; *l = ll;
}

// ---------------------------------------------------------------------------
// Kernel 1: w_q [2048][256] f32 -> B-fragment-packed hi/lo f16 arrays.
// off(n,k) = (((k>>5)*16 + (n>>4))*64 + ((k>>3)&3)*16 + (n&15))*8 + (k&7)
__global__ void prep_w(const float* __restrict__ w, _Float16* __restrict__ whp,
                       _Float16* __restrict__ wlp) {
    const int tid = blockIdx.x * 256 + threadIdx.x;
    const int f    = tid & 15;
    const int q    = (tid >> 4) & 3;
    const int ngrp = (tid >> 6) & 15;
    const int kcs  = tid >> 10;
    const int n = ngrp * 16 + f;
    const int k = kcs * 32 + q * 8;
    f16x8 h, l;
#pragma unroll
    for (int j = 0; j < 8; ++j) {
        float v = w[(size_t)(k + j) * NQ + n];
        _Float16 s = (_Float16)v;
        h[j] = s;
        l[j] = (_Float16)(v - (float)s);
    }
    *(f16x8*)(whp + (size_t)tid * 8) = h;
    *(f16x8*)(wlp + (size_t)tid * 8) = l;
}

// ---------------------------------------------------------------------------
// Kernel 2 (fused): query GEMM (3-pass f16-split MFMA) + logits + top-2 +
// softmax + scatter. BM=64, BN=256, BK=128 (16 barrier intervals), ping-pong
// LDS, per-ks rolling B prefetch (no reg-copy rotation), setprio on MFMA
// clusters. grid 256, 512 threads (8 waves, wave = 32-col n-slice).
__global__ __launch_bounds__(512) void gemm_fused(
    const float* __restrict__ x, const _Float16* __restrict__ whp,
    const _Float16* __restrict__ wlp, const float* __restrict__ bq,
    const float* __restrict__ keys, const float* __restrict__ noise,
    float* __restrict__ gate, float* __restrict__ idxout) {
    // LDS: ping-pong A buffers [0,64K): buf b at b*32KB = {Ah 16KB, Al 16KB}.
    // Epilogue: qs f32 [64][260] (66.56KB) aliases everything; LG [64][65] aliases qs base.
    __shared__ __align__(16) char smem[66560];

    const int t = threadIdx.x;
    const int lane = t & 63;
    const int wv = t >> 6;              // 0..7, n-slice [32*wv, 32*wv+32)
    const int m0 = blockIdx.x * 64;
    const int f = lane & 15;
    const int qq = lane >> 4;           // 0..3

    // staging: thread owns k-octet soct (8 f32) of rows {srow, srow+32}
    const int srow = t >> 4;            // 0..31
    const int soct = t & 15;            // 0..15
    const int swoff = (soct ^ (srow & 7)) * 8;     // f16 units (XOR swizzle)
    const f32x4* xq0 = (const f32x4*)(x + (size_t)(m0 + srow) * KD + soct * 8);
    const f32x4* xq1 = (const f32x4*)(x + (size_t)(m0 + srow + 32) * KD + soct * 8);

    // B pointers (frag-packed): frag(kc32, ngrp) at whp + kc32*8192 + ngrp*512 + lane*8
    const _Float16* bph = whp + (size_t)(2 * wv) * 512 + lane * 8;
    const _Float16* bpl = wlp + (size_t)(2 * wv) * 512 + lane * 8;

    f32x4 acc[4][2];
#pragma unroll
    for (int mt = 0; mt < 4; ++mt)
#pragma unroll
        for (int nt = 0; nt < 2; ++nt) acc[mt][nt] = {0.f, 0.f, 0.f, 0.f};

    // ---- prologue: tile 0 -> buf0; preload x(tile1)
    f32x4 a0 = __builtin_nontemporal_load(xq0);
    f32x4 a1 = __builtin_nontemporal_load(xq0 + 1);
    f32x4 b0 = __builtin_nontemporal_load(xq1);
    f32x4 b1 = __builtin_nontemporal_load(xq1 + 1);
    {
        _Float16* Ah = (_Float16*)smem;
        _Float16* Al = Ah + 8192;
        f16x8 h8, l8;
        split8v(a0, a1, &h8, &l8);
        *(f16x8*)(Ah + srow * 128 + swoff) = h8;
        *(f16x8*)(Al + srow * 128 + swoff) = l8;
        split8v(b0, b1, &h8, &l8);
        *(f16x8*)(Ah + (srow + 32) * 128 + swoff) = h8;
        *(f16x8*)(Al + (srow + 32) * 128 + swoff) = l8;
    }
    a0 = __builtin_nontemporal_load(xq0 + 32);
    a1 = __builtin_nontemporal_load(xq0 + 33);
    b0 = __builtin_nontemporal_load(xq1 + 32);
    b1 = __builtin_nontemporal_load(xq1 + 33);
    __syncthreads();  // one-time full drain

    // rolling B fragment registers (unroll-static double buffer)
    f16x8 bh[2][2], bl[2][2];
#pragma unroll
    for (int nt = 0; nt < 2; ++nt) {
        bh[0][nt] = *(const f16x8*)(bph + nt * 512);
        bl[0][nt] = *(const f16x8*)(bpl + nt * 512);
    }

    // ---- K loop: 16 iterations of BK=128 (4 ks-steps of 32 each)
    for (int i = 0; i < 16; ++i) {
        _Float16* AhC = (_Float16*)smem + (i & 1) * 16384;
        _Float16* AlC = AhC + 8192;
        _Float16* AhN = (_Float16*)smem + ((i & 1) ^ 1) * 16384;
        _Float16* AlN = AhN + 8192;

        // stage tile i+1 into the other buffer (x regs loaded 2 iters ago)
        if (i < 15) {
            f16x8 h8, l8;
            split8v(a0, a1, &h8, &l8);
            *(f16x8*)(AhN + srow * 128 + swoff) = h8;
            *(f16x8*)(AlN + srow * 128 + swoff) = l8;
            split8v(b0, b1, &h8, &l8);
            *(f16x8*)(AhN + (srow + 32) * 128 + swoff) = h8;
            *(f16x8*)(AlN + (srow + 32) * 128 + swoff) = l8;
        }
        // prefetch x tile i+2 (non-temporal: don't thrash whp out of L2)
        if (i < 14) {
            a0 = __builtin_nontemporal_load(xq0 + (i + 2) * 32);
            a1 = __builtin_nontemporal_load(xq0 + (i + 2) * 32 + 1);
            b0 = __builtin_nontemporal_load(xq1 + (i + 2) * 32);
            b1 = __builtin_nontemporal_load(xq1 + (i + 2) * 32 + 1);
        }
        // compute on current buffer: 4 ks-steps, rolling B prefetch (dist 1)
#pragma unroll
        for (int ks = 0; ks < 4; ++ks) {
            const int cs = ks & 1;
            const int ns = cs ^ 1;
            int kcn = i * 4 + ks + 1;
            if (kcn > 63) kcn = 63;  // branchless clamp: one redundant load at end
            const size_t bo = (size_t)kcn * 8192;
#pragma unroll
            for (int nt = 0; nt < 2; ++nt) {
                bh[ns][nt] = *(const f16x8*)(bph + bo + nt * 512);
                bl[ns][nt] = *(const f16x8*)(bpl + bo + nt * 512);
            }
            f16x8 ah[4], al[4];
#pragma unroll
            for (int mt = 0; mt < 4; ++mt) {
                const int ab = (mt * 16 + f) * 128 + (((ks * 4 + qq) ^ (f & 7)) * 8);
                ah[mt] = *(const f16x8*)(AhC + ab);
                al[mt] = *(const f16x8*)(AlC + ab);
            }
            __builtin_amdgcn_s_setprio(1);
#pragma unroll
            for (int mt = 0; mt < 4; ++mt)
#pragma unroll
                for (int nt = 0; nt < 2; ++nt) {
                    acc[mt][nt] = __builtin_amdgcn_mfma_f32_16x16x32_f16(ah[mt], bh[cs][nt], acc[mt][nt], 0, 0, 0);
                    acc[mt][nt] = __builtin_amdgcn_mfma_f32_16x16x32_f16(ah[mt], bl[cs][nt], acc[mt][nt], 0, 0, 0);
                    acc[mt][nt] = __builtin_amdgcn_mfma_f32_16x16x32_f16(al[mt], bh[cs][nt], acc[mt][nt], 0, 0, 0);
                }
            __builtin_amdgcn_s_setprio(0);
        }
        // raw barrier: publish LDS writes (lgkmcnt(0)) WITHOUT draining vmcnt,
        // so B/x prefetches stay in flight across the barrier.
        asm volatile("" ::: "memory");
        __builtin_amdgcn_s_waitcnt(0xC07F);  // lgkmcnt(0) only
        __builtin_amdgcn_s_barrier();
        asm volatile("" ::: "memory");
    }

    // ---- epilogue: +bias, park q tile in LDS (aliases A buffers; final barrier covers)
    float* qs = (float*)smem;  // [64][260]
#pragma unroll
    for (int nt = 0; nt < 2; ++nt) {
        int col = wv * 32 + nt * 16 + f;
        float bias = bq[col];
#pragma unroll
        for (int mt = 0; mt < 4; ++mt)
#pragma unroll
            for (int r = 0; r < 4; ++r)
                qs[(mt * 16 + qq * 4 + r) * 260 + col] = acc[mt][nt][r] + bias;
    }
    __syncthreads();

    // ---- logits: waves 0..3, wave covers 16 experts x 64 rows
    const int e = wv * 16 + f;
    f32x4 a2[4];
#pragma unroll
    for (int mt = 0; mt < 4; ++mt) a2[mt] = {0.f, 0.f, 0.f, 0.f};
    if (wv < 4) {
        const float* kp = keys + (size_t)e * NQ + qq * 8;
        for (int kc = 0; kc < NQ; kc += 32) {
            f32x4 k0 = *(const f32x4*)(kp + kc);
            f32x4 k1 = *(const f32x4*)(kp + kc + 4);
            f16x8 bh2, bl2;
            split8v(k0, k1, &bh2, &bl2);
#pragma unroll
            for (int mt = 0; mt < 4; ++mt) {
                const float* ap = qs + (mt * 16 + f) * 260 + kc + qq * 8;
                f32x4 q0 = *(const f32x4*)ap;
                f32x4 q1 = *(const f32x4*)(ap + 4);
                f16x8 ah2, al2;
                split8v(q0, q1, &ah2, &al2);
                a2[mt] = __builtin_amdgcn_mfma_f32_16x16x32_f16(ah2, bh2, a2[mt], 0, 0, 0);
                a2[mt] = __builtin_amdgcn_mfma_f32_16x16x32_f16(ah2, bl2, a2[mt], 0, 0, 0);
                a2[mt] = __builtin_amdgcn_mfma_f32_16x16x32_f16(al2, bh2, a2[mt], 0, 0, 0);
            }
        }
    }
    __syncthreads();  // all qs reads done before LG (aliases qs base) is written

    float* LG = (float*)smem;  // [64][65]
    if (wv < 4) {
#pragma unroll
        for (int mt = 0; mt < 4; ++mt)
#pragma unroll
            for (int r = 0; r < 4; ++r) {
                int row = mt * 16 + qq * 4 + r;
                LG[row * 65 + e] = a2[mt][r] * INV_SQRT_DQ +
                                   NOISE_STD_C * noise[(size_t)(m0 + row) * NE + e];
            }
    }
    __syncthreads();

    // ---- top-2 + softmax + scatter: 8 waves x 8 rows, lane = expert
    for (int i = 0; i < 8; ++i) {
        int r = wv * 8 + i;
        float v = LG[r * 65 + lane];
        float v1 = v; int i1 = lane;
#pragma unroll
        for (int off = 32; off; off >>= 1) {
            float ov = __shfl_xor(v1, off);
            int oi = __shfl_xor(i1, off);
            if (ov > v1 || (ov == v1 && oi < i1)) { v1 = ov; i1 = oi; }
        }
        float v2 = (lane == i1) ? -1e30f : v;
        int i2 = lane;
#pragma unroll
        for (int off = 32; off; off >>= 1) {
            float ov = __shfl_xor(v2, off);
            int oi = __shfl_xor(i2, off);
            if (ov > v2 || (ov == v2 && oi < i2)) { v2 = ov; i2 = oi; }
        }
        float ex = expf(v2 - v1);           // v2 <= v1, stable
        float p1 = 1.0f / (1.0f + ex);
        float p2 = ex * p1;
        float g = (lane == i1) ? p1 : ((lane == i2) ? p2 : 0.0f);
        gate[(size_t)(m0 + r) * NE + lane] = g;
        if (lane == 0) {
            float2 ii = make_float2((float)i1, (float)i2);
            *(float2*)(idxout + (size_t)(m0 + r) * 2) = ii;
        }
    }
}

// ---------------------------------------------------------------------------
extern "C" void kernel_launch(void* const* d_in, const int* in_sizes, int n_in,
                              void* d_out, int out_size, void* d_ws, size_t ws_size,
                              hipStream_t stream) {
    const float* x     = (const float*)d_in[0];
    const float* noise = (const float*)d_in[1];
    const float* w_q   = (const float*)d_in[2];
    const float* b_q   = (const float*)d_in[3];
    const float* keys  = (const float*)d_in[4];
    float* out = (float*)d_out;

    char* ws = (char*)d_ws;
    _Float16* whp = (_Float16*)ws;                 // 1 MB, frag-packed hi
    _Float16* wlp = (_Float16*)(ws + (1u << 20));  // 1 MB, frag-packed lo

    prep_w<<<256, 256, 0, stream>>>(w_q, whp, wlp);
    gemm_fused<<<256, 512, 0, stream>>>(x, whp, wlp, b_q, keys, noise,
                                        out, out + (size_t)MROWS * NE);
}